// Round 9
// baseline (14247.943 us; speedup 1.0000x reference)
//
#include <hip/hip_runtime.h>

#define NPER 512
#define CDIM 256
#define BG   64
#define NB   256
#define TPB  256
#define GW   4      // graphs per cluster == waves per block (wave w owns graph gb+w)
#define CW   16     // channels per member block
#define WST  258    // col-major weight stride (256 + 2)
#define CAP  64

// Zero the tagged exchange buffers (tags must be 0 so step-1 polls for tag 0
// succeed immediately, and stale tags from a previous replay can't alias).
__global__ void init_ws(unsigned long long* p, int n) {
    int i = blockIdx.x * blockDim.x + threadIdx.x;
    if (i < n) p[i] = 0ULL;
}

__device__ __forceinline__ float ld_sc(const float* p) {
    return __hip_atomic_load((const float*)p, __ATOMIC_RELAXED, __HIP_MEMORY_SCOPE_AGENT);
}
__device__ __forceinline__ void st_sc(float* p, float v) {
    __hip_atomic_store(p, v, __ATOMIC_RELAXED, __HIP_MEMORY_SCOPE_AGENT);
}
// One 8B atomic store carries (value, tag) together: no fence / store-order
// assumption anywhere. Agent scope (LLC-homed) -- the proven r1/r8 transport;
// faster-cache variants were falsified in r2-r4.
__device__ __forceinline__ void st_tag(float* buf, int idx, float v, unsigned tg) {
    unsigned long long u = ((unsigned long long)tg << 32) |
                           (unsigned long long)__float_as_uint(v);
    __hip_atomic_store((unsigned long long*)(buf + 2 * (size_t)idx), u,
                       __ATOMIC_RELAXED, __HIP_MEMORY_SCOPE_AGENT);
}

// Wave-private poll of ONE graph's 256 pairs (4 per lane, pair base pb).
// Wave spins alone on __all -- no block barrier anywhere. Detection and data
// arrive in the same LLC round-trip (tag+value in one atomic 8B pair).
// Single-buffer WAR safety: unchanged r1 argument per independent chain
// {wave w of the cluster's 16 blocks}: the step chain (hnew->z->agg->hnew)
// means a producer writing step t has observed all step-t inputs, so every
// consumer in its chain finished its step t-1 reads of this buffer.
__device__ __forceinline__ void poll4(const float* buf, unsigned tg, int pb,
                                      int L, float* vals) {
    unsigned long long u[4];
    int ok = 0;
    do {
        if (!ok) {
            #pragma unroll
            for (int j = 0; j < 4; ++j)
                u[j] = __hip_atomic_load(
                    (const unsigned long long*)(buf + 2 * (size_t)(pb + j * 64 + L)),
                    __ATOMIC_RELAXED, __HIP_MEMORY_SCOPE_AGENT);
            ok = 1;
            #pragma unroll
            for (int j = 0; j < 4; ++j) ok &= ((unsigned)(u[j] >> 32) == tg);
        }
    } while (!__all(ok));
    #pragma unroll
    for (int j = 0; j < 4; ++j) vals[j] = __uint_as_float((unsigned)(u[j] & 0xffffffffu));
}

__global__ __launch_bounds__(TPB, 1)
void gnn_fp32(const float* __restrict__ x,
              const float* __restrict__ W1g, const float* __restrict__ b1g,
              const float* __restrict__ W2g, const float* __restrict__ b2g,
              const float* __restrict__ wihg, const float* __restrict__ bihg,
              const float* __restrict__ whhg, const float* __restrict__ bhhg,
              const int* __restrict__ src_f, const int* __restrict__ gid_f,
              const float* __restrict__ msk_f,
              const int* __restrict__ src_b, const int* __restrict__ gid_b,
              const float* __restrict__ msk_b,
              int Kf, int Kb,
              float* __restrict__ hx,
              float* __restrict__ xh, float* __restrict__ xz,
              float* __restrict__ xa, float* __restrict__ ring)
{
    // Read-only after the single init barrier:
    __shared__ float sh_w[128 * WST];   // rows: 0-47 wih, 48-95 whh, 96-111 W1, 112-127 W2
    __shared__ float sh_bih[48], sh_bhh[48], sh_b1[CW], sh_b2[CW];
    // Wave-private (wave w touches only index [w]; no cross-wave access):
    __shared__ float sh_act[GW][CDIM];
    __shared__ float sh_hold[GW][CDIM];
    __shared__ float sh_gi[GW][48];
    __shared__ float sh_gh[GW][48];
    __shared__ int   sh_list[GW][CAP];
    __shared__ int   sh_cnt[GW];

    const int tid   = threadIdx.x;
    const int w     = tid >> 6;          // wave = local graph index
    const int L     = tid & 63;
    const int out   = L >> 2;            // 0..15 output row within 16-row round
    const int l4    = L & 3;             // k-split lane
    const int cl    = blockIdx.x & 15;   // 16 clusters
    const int mb    = blockIdx.x >> 4;   // 16 member blocks per cluster
    const int gb    = cl * GW;
    const int gwg   = gb + w;            // this wave's global graph id
    const int cbase = mb * CW;
    const int pb    = gwg * CDIM;        // exchange pair base for this graph

    float* ring_blk = ring + (size_t)blockIdx.x * 64 * GW * CW;

    // ---- stage weights col-major into LDS, once (cooperative) ----
    for (int e = tid; e < 128 * 256; e += TPB) {
        int r = e >> 8, k = e & 255;
        const float* sp; int grow;
        if (r < 48)       { sp = wihg; grow = (r >> 4) * CDIM + cbase + (r & 15); }
        else if (r < 96)  { sp = whhg; grow = ((r - 48) >> 4) * CDIM + cbase + ((r - 48) & 15); }
        else if (r < 112) { sp = W1g;  grow = cbase + (r - 96); }
        else              { sp = W2g;  grow = cbase + (r - 112); }
        sh_w[r * WST + k] = sp[(size_t)grow * CDIM + k];
    }
    if (tid < 48) {
        sh_bih[tid] = bihg[(tid >> 4) * CDIM + cbase + (tid & 15)];
        sh_bhh[tid] = bhhg[(tid >> 4) * CDIM + cbase + (tid & 15)];
    } else if (tid < 64) {
        sh_b1[tid - 48] = b1g[cbase + tid - 48];
        sh_b2[tid - 48] = b2g[cbase + tid - 48];
    }
    __syncthreads();   // the ONLY block barrier; sh_w/biases read-only after

    float keep = 0.f;  // live in lanes 0..15 (channel cbase+L of graph gwg)

    for (int pass = 0; pass < 2; ++pass) {
        const int* srcA   = pass ? src_b : src_f;
        const int* gidA   = pass ? gid_b : gid_f;
        const float* mskA = pass ? msk_b : msk_f;
        const int K = pass ? Kb : Kf;

        for (int s = 0; s < NPER; ++s) {
            const int node = pass ? (NPER - 1 - s) : s;
            const unsigned tg = (unsigned)(pass * NPER + s + 1);
            const bool has_prev = !(pass == 0 && s == 0);
            const int prev = (s > 0) ? (pass ? node + 1 : node - 1) : (NPER - 1);

            // ======= P1: deferred hx write; hold prefetch; poll hnew; stage;
            //         W1 -> z tagged; edge filter (covers z flight) =======
            if (has_prev && L < 16)
                st_sc(&hx[((size_t)gwg * NPER + prev) * CDIM + cbase + L], keep);
            float holdv[4];
            if (pass == 1 && s > 0) {            // issue early: completes under the poll
                #pragma unroll
                for (int j = 0; j < 4; ++j)
                    holdv[j] = ld_sc(&hx[((size_t)gwg * NPER + node) * CDIM + j * 64 + L]);
            }
            if (L == 0) sh_cnt[w] = 0;

            float hv[4];
            poll4(xh, tg - 1, pb, L, hv);        // tag 0 at (pass0,s0): zeros, harmless
            #pragma unroll
            for (int j = 0; j < 4; ++j) sh_act[w][j * 64 + L] = hv[j];
            if (pass == 0) {                     // h_old = x (read-only cached loads)
                const float* op = x + ((size_t)gwg * NPER + node) * CDIM + 4 * L;
                float4 h0 = *(const float4*)op;
                float* d = &sh_hold[w][4 * L];
                d[0] = h0.x; d[1] = h0.y; d[2] = h0.z; d[3] = h0.w;
            } else if (s == 0) {                 // h_old(node 511) == hnew from fwd end
                #pragma unroll
                for (int j = 0; j < 4; ++j) sh_hold[w][j * 64 + L] = hv[j];
            } else {
                #pragma unroll
                for (int j = 0; j < 4; ++j) sh_hold[w][j * 64 + L] = holdv[j];
            }

            {   // W1 GEMM: 16 rows, 4-lane k-split (act reads broadcast; wgt <=2-way)
                const float* wr = &sh_w[(96 + out) * WST];
                const float* ar = sh_act[w];
                float acc = 0.f;
                #pragma unroll 16
                for (int j = 0; j < 64; ++j) { int k = l4 + 4 * j; acc += wr[k] * ar[k]; }
                acc += __shfl_xor(acc, 1, 64);
                acc += __shfl_xor(acc, 2, 64);
                if (l4 == 0) {
                    float v = acc + sh_b1[out];
                    st_tag(xz, pb + cbase + out, v > 0.f ? v : 0.f, tg);
                }
            }
            for (int e = L; e < K; e += 64) {    // edge filter for this wave's graph
                size_t off = (size_t)s * K + e;
                if (mskA[off] != 0.f && gidA[off] == gwg) {
                    int p = atomicAdd(&sh_cnt[w], 1);
                    if (p < CAP) sh_list[w][p] = srcA[off] & 63;
                }
            }

            // ======= P2: poll z; ring = relu(W2 z); aggregate -> agg tagged =======
            float zv[4];
            poll4(xz, tg, pb, L, zv);
            #pragma unroll
            for (int j = 0; j < 4; ++j) sh_act[w][j * 64 + L] = zv[j];
            {   // W2 GEMM -> ring[prev & 63] (this wave's graph row)
                const float* wr = &sh_w[(112 + out) * WST];
                const float* ar = sh_act[w];
                float acc = 0.f;
                #pragma unroll 16
                for (int j = 0; j < 64; ++j) { int k = l4 + 4 * j; acc += wr[k] * ar[k]; }
                acc += __shfl_xor(acc, 1, 64);
                acc += __shfl_xor(acc, 2, 64);
                if (l4 == 0) {
                    float v = acc + sh_b2[out];
                    ring_blk[((prev & 63) * GW + w) * CW + out] = v > 0.f ? v : 0.f;
                }
            }
            // Ring store -> read is wave-internal; drain vm queue so the fresh
            // slot (prev&63, referenced by the mandatory j-1 edge) is visible.
            // Same-CU plain store->load visibility is proven by r1-r8.
            asm volatile("s_waitcnt vmcnt(0)" ::: "memory");
            if (L < 16) {
                int n = sh_cnt[w]; if (n > CAP) n = CAP;
                float a = 0.f;
                for (int i = 0; i < n; ++i)
                    a += ring_blk[(sh_list[w][i] * GW + w) * CW + L];
                st_tag(xa, pb + cbase + L, a, tg);
            }

            // ======= P3: gh GEMM (covers agg flight); poll agg; gi GEMM; gates =======
            #pragma unroll
            for (int r = 0; r < 3; ++r) {        // gh: 48 rows in 3 rounds of 16
                const int rr = r * 16 + out;
                const float* wr = &sh_w[(48 + rr) * WST];
                const float* hr = sh_hold[w];
                float acc = 0.f;
                #pragma unroll 16
                for (int j = 0; j < 64; ++j) { int k = l4 + 4 * j; acc += wr[k] * hr[k]; }
                acc += __shfl_xor(acc, 1, 64);
                acc += __shfl_xor(acc, 2, 64);
                if (l4 == 0) sh_gh[w][rr] = acc + sh_bhh[rr];
            }
            float av[4];
            poll4(xa, tg, pb, L, av);
            #pragma unroll
            for (int j = 0; j < 4; ++j) sh_act[w][j * 64 + L] = av[j];
            #pragma unroll
            for (int r = 0; r < 3; ++r) {        // gi: 48 rows in 3 rounds of 16
                const int rr = r * 16 + out;
                const float* wr = &sh_w[rr * WST];
                const float* ar = sh_act[w];
                float acc = 0.f;
                #pragma unroll 16
                for (int j = 0; j < 64; ++j) { int k = l4 + 4 * j; acc += wr[k] * ar[k]; }
                acc += __shfl_xor(acc, 1, 64);
                acc += __shfl_xor(acc, 2, 64);
                if (l4 == 0) sh_gi[w][rr] = acc + sh_bih[rr];
            }
            if (L < 16) {
                float ir = sh_gi[w][L], iz = sh_gi[w][16 + L], in_ = sh_gi[w][32 + L];
                float hr = sh_gh[w][L], hz = sh_gh[w][16 + L], hn  = sh_gh[w][32 + L];
                float hold = sh_hold[w][cbase + L];
                float rg = 1.f / (1.f + expf(-(ir + hr)));
                float zg = 1.f / (1.f + expf(-(iz + hz)));
                float nn = tanhf(in_ + rg * hn);
                keep = (1.f - zg) * nn + zg * hold;
                // pass0->pass1 hx handoff: drain this wave's hx stores before
                // the tag that releases chain members into pass 1.
                if (pass == 0 && s == NPER - 1)
                    asm volatile("s_waitcnt vmcnt(0)" ::: "memory");
                st_tag(xh, pb + cbase + L, keep, tg);
            }
        }
    }
    if (L < 16)
        st_sc(&hx[((size_t)gwg * NPER + 0) * CDIM + cbase + L], keep);
}

// ---------------- fallback (round-1 structure, known-correct) ----------------
__global__ __launch_bounds__(512)
void gnn_fallback(const float* __restrict__ x,
                  const float* __restrict__ W1, const float* __restrict__ b1,
                  const float* __restrict__ W2, const float* __restrict__ b2,
                  const float* __restrict__ w_ih, const float* __restrict__ b_ih,
                  const float* __restrict__ w_hh, const float* __restrict__ b_hh,
                  const int* __restrict__ src_f, const int* __restrict__ gid_f,
                  const float* __restrict__ msk_f,
                  const int* __restrict__ src_b, const int* __restrict__ gid_b,
                  const float* __restrict__ msk_b,
                  int Kf, int Kb, float* __restrict__ hx)
{
    const int b = blockIdx.x, t = threadIdx.x;
    __shared__ float sh_ring[64 * CDIM];
    __shared__ float sh_agg[CDIM], sh_hold[CDIM], sh_hnew[CDIM], sh_h1[CDIM];
    __shared__ float sh_gi[3 * CDIM], sh_gh[3 * CDIM];
    __shared__ int   sh_list[256];
    __shared__ int   sh_cnt;
    const size_t base = (size_t)b * NPER * CDIM;
    {
        const float4* x4 = (const float4*)(x + base);
        float4* h4 = (float4*)(hx + base);
        for (int i = t; i < NPER * CDIM / 4; i += 512) h4[i] = x4[i];
    }
    if (t == 0) sh_cnt = 0;
    __syncthreads();
    for (int pass = 0; pass < 2; ++pass) {
        const int* srcA = pass ? src_b : src_f;
        const int* gidA = pass ? gid_b : gid_f;
        const float* mskA = pass ? msk_b : msk_f;
        const int K = pass ? Kb : Kf;
        for (int step = 0; step < NPER; ++step) {
            const int node = pass ? (NPER - 1 - step) : step;
            if (t < CDIM / 4)
                ((float4*)sh_hold)[t] = ((const float4*)(hx + base + (size_t)node * CDIM))[t];
            for (int k = t; k < K; k += 512) {
                size_t off = (size_t)step * K + k;
                if (mskA[off] != 0.f && gidA[off] == b) {
                    int p = atomicAdd(&sh_cnt, 1);
                    if (p < 256) sh_list[p] = srcA[off] & 63;
                }
            }
            __syncthreads();
            int cnt = sh_cnt; if (cnt > 256) cnt = 256;
            if (t < CDIM) {
                float a = 0.f;
                for (int e = 0; e < cnt; ++e) a += sh_ring[sh_list[e] * CDIM + t];
                sh_agg[t] = a;
            }
            __syncthreads();
            #pragma unroll
            for (int d = 0; d < 3; ++d) {
                const int idx = t + d * 512;
                const float *wrow, *inv; float bias; float* outp;
                if (idx < 3 * CDIM) { wrow = w_ih + (size_t)idx * CDIM; inv = sh_agg; bias = b_ih[idx]; outp = &sh_gi[idx]; }
                else { int r = idx - 3 * CDIM; wrow = w_hh + (size_t)r * CDIM; inv = sh_hold; bias = b_hh[r]; outp = &sh_gh[r]; }
                float acc = 0.f;
                const float4* w4 = (const float4*)wrow; const float4* i4 = (const float4*)inv;
                #pragma unroll 8
                for (int j = 0; j < CDIM / 4; ++j) {
                    float4 w = w4[j], v = i4[j];
                    acc += w.x * v.x + w.y * v.y + w.z * v.z + w.w * v.w;
                }
                *outp = acc + bias;
            }
            __syncthreads();
            if (t < CDIM) {
                float ir = sh_gi[t], iz = sh_gi[t + CDIM], in_ = sh_gi[t + 2 * CDIM];
                float hr = sh_gh[t], hz = sh_gh[t + CDIM], hn = sh_gh[t + 2 * CDIM];
                float r = 1.f / (1.f + expf(-(ir + hr)));
                float z = 1.f / (1.f + expf(-(iz + hz)));
                float n = tanhf(in_ + r * hn);
                float hv = (1.f - z) * n + z * sh_hold[t];
                sh_hnew[t] = hv;
                hx[base + (size_t)node * CDIM + t] = hv;
            }
            if (t == 511) sh_cnt = 0;
            __syncthreads();
            if (t < CDIM) {
                const float4* w4 = (const float4*)(W1 + (size_t)t * CDIM);
                const float4* i4 = (const float4*)sh_hnew;
                float acc = 0.f;
                #pragma unroll 8
                for (int j = 0; j < CDIM / 4; ++j) {
                    float4 w = w4[j], v = i4[j];
                    acc += w.x * v.x + w.y * v.y + w.z * v.z + w.w * v.w;
                }
                acc += b1[t];
                sh_h1[t] = acc > 0.f ? acc : 0.f;
            }
            __syncthreads();
            if (t < CDIM) {
                const float4* w4 = (const float4*)(W2 + (size_t)t * CDIM);
                const float4* i4 = (const float4*)sh_h1;
                float acc = 0.f;
                #pragma unroll 8
                for (int j = 0; j < CDIM / 4; ++j) {
                    float4 w = w4[j], v = i4[j];
                    acc += w.x * v.x + w.y * v.y + w.z * v.z + w.w * v.w;
                }
                acc += b2[t];
                sh_ring[(node & 63) * CDIM + t] = acc > 0.f ? acc : 0.f;
            }
            __syncthreads();
        }
    }
}

extern "C" void kernel_launch(void* const* d_in, const int* in_sizes, int n_in,
                              void* d_out, int out_size, void* d_ws, size_t ws_size,
                              hipStream_t stream) {
    const float* x    = (const float*)d_in[0];
    const float* W1   = (const float*)d_in[1];
    const float* b1   = (const float*)d_in[2];
    const float* W2   = (const float*)d_in[3];
    const float* b2   = (const float*)d_in[4];
    const float* w_ih = (const float*)d_in[5];
    const float* b_ih = (const float*)d_in[6];
    const float* w_hh = (const float*)d_in[7];
    const float* b_hh = (const float*)d_in[8];
    const int*   src_f = (const int*)d_in[9];
    const int*   gid_f = (const int*)d_in[10];
    const float* msk_f = (const float*)d_in[11];
    const int*   src_b = (const int*)d_in[12];
    const int*   gid_b = (const int*)d_in[13];
    const float* msk_b = (const float*)d_in[14];

    const int Kf = in_sizes[9]  / NPER;
    const int Kb = in_sizes[12] / NPER;
    float* hx = (float*)d_out;

    char* ws = (char*)d_ws;
    // 4096 pad + 3 tagged exchange buffers (64 graphs x 256 ch x 8B) + ring
    const size_t need = 4096 + 3 * (size_t)BG * CDIM * 8 + (size_t)NB * 64 * GW * CW * 4;
    if (ws_size >= need) {
        float* xh   = (float*)(ws + 4096);
        float* xz   = xh + (size_t)BG * CDIM * 2;
        float* xa   = xz + (size_t)BG * CDIM * 2;
        float* ring = xa + (size_t)BG * CDIM * 2;
        // 3 * 64 * 256 = 49152 u64 pairs to zero; 192 * 256 threads covers exactly.
        init_ws<<<192, 256, 0, stream>>>((unsigned long long*)(ws + 4096), 3 * BG * CDIM);
        gnn_fp32<<<NB, TPB, 0, stream>>>(
            x, W1, b1, W2, b2, w_ih, b_ih, w_hh, b_hh,
            src_f, gid_f, msk_f, src_b, gid_b, msk_b,
            Kf, Kb, hx, xh, xz, xa, ring);
    } else {
        gnn_fallback<<<BG, 512, 0, stream>>>(
            x, W1, b1, W2, b2, w_ih, b_ih, w_hh, b_hh,
            src_f, gid_f, msk_f, src_b, gid_b, msk_b,
            Kf, Kb, hx);
    }
}